// Round 7
// baseline (1808.618 us; speedup 1.0000x reference)
//
#include <hip/hip_runtime.h>
#include <cstddef>
#include <cstdint>

#define TS 256
#define NB 1024

// ---- LDS layout (float offsets) ----
// Bank rule: ds_read_b128 per-lane stride S floats -> 16B slot = (S/4*lane)%8.
// Need S/4 odd (coprime with 8). 60->15 ok, 92->23 ok, 28->7 ok.
// Fixed this round: IC/OC 96->100 (25), COMP/OUT 32->36 (9), SENSE 8->12 (3).
#define OW_SENSE 0        // 30x12
#define OW_ZR    360      // 60x60: z rows 0-29, r rows 30-59
#define OW_HE    3960     // 60x60: h rows 0-29, expand rows 30-59 (cols 27+ zero)
#define OW_PHI   7560     // 90x92
#define OW_IC    15840    // 27x100 (k-split halves at +0/+48)
#define OW_I3    18540    // 90x28: iS 0-29, iM 30-59, iD 60-89
#define OW_COMP  21060    // 27x36
#define OW_OC    22032    // 27x100
#define OW_OE    24732    // 30x28
#define OW_OUT   25572    // 4x36
#define OACT     25716
#define ACT_STRIDE 568    // 16B-aligned (568*4 = 142*16)
// per-row activation offsets
#define A_COMB 0     // sensed 0-29, M 30-59
#define A_HIN  60    // sensed 0-29, r*M 30-59
#define A_CMP  120   // compressed 0-26, zeros 27-59 (padded for unified P3)
#define A_AS   180   // 92: S_new, M_new, D (+2 pad)
#define A_GT   272   // 96: gated (+6 pad for k-split)
#define A_IC   368   // 32
#define A_CO   400   // 96: combined_out (+6 pad)
#define A_OC   496   // 32
#define A_DEC  528   // 32
#define A_OBS  560   // 8
#define NROWS_BLK 8
#define SM_TOTAL (OACT + NROWS_BLK*ACT_STRIDE)   // 30260 floats = 121040 B

#define FMA4(A_, W_, X_) do { \
    (A_).x = fmaf((W_).x, (X_).x, (A_).x); \
    (A_).y = fmaf((W_).y, (X_).y, (A_).y); \
    (A_).z = fmaf((W_).z, (X_).z, (A_).z); \
    (A_).w = fmaf((W_).w, (X_).w, (A_).w); } while (0)

__device__ __forceinline__ float red4(float4 a) { return (a.x + a.y) + (a.z + a.w); }
__device__ __forceinline__ float ftanh(float x) {
    float e = __expf(2.0f * x);
    return 1.0f - 2.0f / (e + 1.0f);
}
__device__ __forceinline__ float fsig(float x) {
    return 1.0f / (1.0f + __expf(-x));
}

__launch_bounds__(256)
__global__ void anima_kernel(
    const float* __restrict__ obs,
    const float* __restrict__ sense_w, const float* __restrict__ sense_b,
    const float* __restrict__ compress_w, const float* __restrict__ compress_b,
    const float* __restrict__ expand_w, const float* __restrict__ expand_b,
    const float* __restrict__ gru_z_w, const float* __restrict__ gru_z_b,
    const float* __restrict__ gru_r_w, const float* __restrict__ gru_r_b,
    const float* __restrict__ gru_h_w, const float* __restrict__ gru_h_b,
    const float* __restrict__ ic_w, const float* __restrict__ ic_b,
    const float* __restrict__ iS_w, const float* __restrict__ iS_b,
    const float* __restrict__ iM_w, const float* __restrict__ iM_b,
    const float* __restrict__ iD_w, const float* __restrict__ iD_b,
    const float* __restrict__ phi_w, const float* __restrict__ phi_b,
    const float* __restrict__ oc_w, const float* __restrict__ oc_b,
    const float* __restrict__ oe_w, const float* __restrict__ oe_b,
    const float* __restrict__ out_w, const float* __restrict__ out_b,
    float* __restrict__ out)
{
    extern __shared__ float sm[];
    const int tid = threadIdx.x;
    const int wid = tid >> 6;
    const int lane = tid & 63;
    // 2 rows per wave: weight LDS reads amortize over both rows.
    const int row0 = blockIdx.x * NROWS_BLK + wid * 2;
    const int row1 = row0 + 1;

    // zero all LDS (pads must be 0)
    for (int i = tid; i < SM_TOTAL; i += 256) sm[i] = 0.0f;
    __syncthreads();

#define LOADW(OFF, SRC, OUTD, K, KP) \
    for (int i = tid; i < (OUTD)*(K); i += 256) { int o = i/(K); int kk = i - o*(K); sm[(OFF) + o*(KP) + kk] = SRC[i]; }
    LOADW(OW_SENSE, sense_w, 30, 8, 12)
    LOADW(OW_ZR, gru_z_w, 30, 60, 60)
    LOADW(OW_ZR + 1800, gru_r_w, 30, 60, 60)
    LOADW(OW_HE, gru_h_w, 30, 60, 60)
    LOADW(OW_HE + 1800, expand_w, 30, 27, 60)
    LOADW(OW_PHI, phi_w, 90, 90, 92)
    LOADW(OW_IC, ic_w, 27, 90, 100)
    LOADW(OW_I3, iS_w, 30, 27, 28)
    LOADW(OW_I3 + 840, iM_w, 30, 27, 28)
    LOADW(OW_I3 + 1680, iD_w, 30, 27, 28)
    LOADW(OW_COMP, compress_w, 27, 30, 36)
    LOADW(OW_OC, oc_w, 27, 90, 100)
    LOADW(OW_OE, oe_w, 30, 27, 28)
    LOADW(OW_OUT, out_w, 4, 30, 36)
#undef LOADW

    float* A0 = sm + OACT + (wid * 2 + 0) * ACT_STRIDE;
    float* A1 = sm + OACT + (wid * 2 + 1) * ACT_STRIDE;
    if (lane < 8) {
        A0[A_OBS + lane] = obs[(size_t)row0 * 8 + lane];
        A1[A_OBS + lane] = obs[(size_t)row1 * 8 + lane];
    }

    // biases into registers (per-lane roles, shared by both rows)
    float b_p1  = (lane < 30) ? sense_b[lane] : 0.0f;
    float b_p2  = (lane < 30) ? gru_z_b[lane] : (lane < 60 ? gru_r_b[lane - 30] : 0.0f);
    float b_cmp = (lane < 27) ? compress_b[lane] : 0.0f;
    float b_p3  = (lane < 30) ? gru_h_b[lane] : (lane < 60 ? expand_b[lane - 30] : 0.0f);
    float b_phi0 = phi_b[lane];
    float b_phi1 = (lane < 26) ? phi_b[64 + lane] : 0.0f;
    float b_ic  = (lane < 27) ? ic_b[lane] : 0.0f;
    float b_i30 = (lane < 30) ? iS_b[lane] : (lane < 60 ? iM_b[lane - 30] : iD_b[lane - 60]);
    float b_i31 = (lane < 26) ? iD_b[4 + lane] : 0.0f;
    float b_oc  = (lane < 27) ? oc_b[lane] : 0.0f;
    float b_oe  = (lane < 30) ? oe_b[lane] : 0.0f;
    float b_out = (lane < 4) ? out_b[lane] : 0.0f;

    float M0 = 0.0f, D0 = 0.0f, z0 = 0.0f;
    float M1 = 0.0f, D1 = 0.0f, z1 = 0.0f;

    __syncthreads();

    for (int t = 0; t < TS; ++t) {
        // ---- P1: sensed = tanh(obs @ sense_w^T + b)
        if (lane < 30) {
            const float4* w4 = (const float4*)(sm + OW_SENSE + lane * 12);
            const float4* xa = (const float4*)(A0 + A_OBS);
            const float4* xb = (const float4*)(A1 + A_OBS);
            float4 a0 = {b_p1, 0.f, 0.f, 0.f};
            float4 a1 = {b_p1, 0.f, 0.f, 0.f};
            #pragma unroll
            for (int i = 0; i < 2; ++i) {
                float4 w = w4[i];
                float4 x0 = xa[i]; FMA4(a0, w, x0);
                float4 x1 = xb[i]; FMA4(a1, w, x1);
            }
            float s0 = ftanh(red4(a0));
            float s1 = ftanh(red4(a1));
            A0[A_COMB + lane] = s0;  A0[A_HIN + lane] = s0;
            A1[A_COMB + lane] = s1;  A1[A_HIN + lane] = s1;
        }
        __syncthreads();

        // prefetch next obs
        float nxt0 = 0.0f, nxt1 = 0.0f;
        if (lane < 8 && t + 1 < TS) {
            nxt0 = obs[((size_t)(t + 1) * NB + row0) * 8 + lane];
            nxt1 = obs[((size_t)(t + 1) * NB + row1) * 8 + lane];
        }

        // ---- P2: z (lanes 0-29), r (lanes 30-59); compress (lanes 0-26)
        if (lane < 60) {
            const float4* w4 = (const float4*)(sm + OW_ZR + lane * 60);
            const float4* xa = (const float4*)(A0 + A_COMB);
            const float4* xb = (const float4*)(A1 + A_COMB);
            float4 a0 = {b_p2, 0.f, 0.f, 0.f};
            float4 a1 = {b_p2, 0.f, 0.f, 0.f};
            #pragma unroll
            for (int i = 0; i < 15; ++i) {
                float4 w = w4[i];
                float4 x0 = xa[i]; FMA4(a0, w, x0);
                float4 x1 = xb[i]; FMA4(a1, w, x1);
            }
            float g0 = fsig(red4(a0));
            float g1 = fsig(red4(a1));
            if (lane < 30) { z0 = g0; z1 = g1; }
            else {
                A0[A_HIN + lane] = g0 * A0[A_COMB + lane];
                A1[A_HIN + lane] = g1 * A1[A_COMB + lane];
            }
        }
        if (lane < 27) {
            const float4* w4 = (const float4*)(sm + OW_COMP + lane * 36);
            const float4* xa = (const float4*)(A0 + A_COMB);
            const float4* xb = (const float4*)(A1 + A_COMB);
            float4 a0 = {b_cmp, 0.f, 0.f, 0.f};
            float4 a1 = {b_cmp, 0.f, 0.f, 0.f};
            #pragma unroll
            for (int i = 0; i < 8; ++i) {
                float4 w = w4[i];
                float4 x0 = xa[i]; FMA4(a0, w, x0);
                float4 x1 = xb[i]; FMA4(a1, w, x1);
            }
            A0[A_CMP + lane] = ftanh(red4(a0));
            A1[A_CMP + lane] = ftanh(red4(a1));
        }
        __syncthreads();

        // ---- P3: h (lanes 0-29 over HIN) / S_new=expand (lanes 30-59 over CMP)
        if (lane < 60) {
            const float4* w4 = (const float4*)(sm + OW_HE + lane * 60);
            const int xoff = (lane < 30 ? A_HIN : A_CMP);
            const float4* xa = (const float4*)(A0 + xoff);
            const float4* xb = (const float4*)(A1 + xoff);
            float4 a0 = {b_p3, 0.f, 0.f, 0.f};
            float4 a1 = {b_p3, 0.f, 0.f, 0.f};
            #pragma unroll
            for (int i = 0; i < 15; ++i) {
                float4 w = w4[i];
                float4 x0 = xa[i]; FMA4(a0, w, x0);
                float4 x1 = xb[i]; FMA4(a1, w, x1);
            }
            float v0 = ftanh(red4(a0));
            float v1 = ftanh(red4(a1));
            if (lane < 30) {
                float m0 = fmaf(z0, v0 - M0, M0);
                float m1 = fmaf(z1, v1 - M1, M1);
                A0[A_AS + 30 + lane] = m0;  A0[A_AS + 60 + lane] = D0;
                A1[A_AS + 30 + lane] = m1;  A1[A_AS + 60 + lane] = D1;
            } else {
                A0[A_AS + (lane - 30)] = v0;
                A1[A_AS + (lane - 30)] = v1;
            }
        }
        __syncthreads();

        // ---- P4: gate = sigmoid(AS @ phi^T + b); GT = AS * gate (90 outs)
        {
            const float4* xa = (const float4*)(A0 + A_AS);
            const float4* xb = (const float4*)(A1 + A_AS);
            const float4* w0 = (const float4*)(sm + OW_PHI + lane * 92);
            const float4* w1 = (const float4*)(sm + OW_PHI + (64 + lane) * 92);
            float4 a00 = {b_phi0, 0.f, 0.f, 0.f};
            float4 a01 = {b_phi1, 0.f, 0.f, 0.f};
            float4 a10 = {b_phi0, 0.f, 0.f, 0.f};
            float4 a11 = {b_phi1, 0.f, 0.f, 0.f};
            #pragma unroll
            for (int i = 0; i < 23; ++i) {
                float4 w = w0[i];
                float4 v = w1[i];
                float4 x0 = xa[i];
                float4 x1 = xb[i];
                FMA4(a00, w, x0); FMA4(a01, v, x0);
                FMA4(a10, w, x1); FMA4(a11, v, x1);
            }
            float g00 = fsig(red4(a00));
            float g10 = fsig(red4(a10));
            A0[A_GT + lane] = A0[A_AS + lane] * g00;
            A1[A_GT + lane] = A1[A_AS + lane] * g10;
            if (lane < 26) {
                float g01 = fsig(red4(a01));
                float g11 = fsig(red4(a11));
                A0[A_GT + 64 + lane] = A0[A_AS + 64 + lane] * g01;
                A1[A_GT + 64 + lane] = A1[A_AS + 64 + lane] * g11;
            }
        }
        __syncthreads();

        // ---- P5: inter_c = tanh(GT @ ic_w^T + b) (27 outs, k-split)
        {
            const int half = lane >> 5, sub = lane & 31;
            const float4* xa = (const float4*)(A0 + A_GT + half * 48);
            const float4* xb = (const float4*)(A1 + A_GT + half * 48);
            const float4* w4 = (const float4*)(sm + OW_IC + sub * 100 + half * 48);
            float4 a0 = {0.f, 0.f, 0.f, 0.f};
            float4 a1 = {0.f, 0.f, 0.f, 0.f};
            #pragma unroll
            for (int i = 0; i < 12; ++i) {
                float4 w = w4[i];
                float4 x0 = xa[i]; FMA4(a0, w, x0);
                float4 x1 = xb[i]; FMA4(a1, w, x1);
            }
            float p0 = red4(a0); p0 += __shfl_xor(p0, 32);
            float p1 = red4(a1); p1 += __shfl_xor(p1, 32);
            if (lane < 27) {
                A0[A_IC + lane] = ftanh(p0 + b_ic);
                A1[A_IC + lane] = ftanh(p1 + b_ic);
            }
        }
        __syncthreads();

        // ---- P6: S_int/M_int/D_new -> CO (90 outs)
        {
            const float4* xa = (const float4*)(A0 + A_IC);
            const float4* xb = (const float4*)(A1 + A_IC);
            const float4* w0 = (const float4*)(sm + OW_I3 + lane * 28);
            const float4* w1 = (const float4*)(sm + OW_I3 + (64 + lane) * 28);
            float4 a00 = {b_i30, 0.f, 0.f, 0.f};
            float4 a01 = {b_i31, 0.f, 0.f, 0.f};
            float4 a10 = {b_i30, 0.f, 0.f, 0.f};
            float4 a11 = {b_i31, 0.f, 0.f, 0.f};
            #pragma unroll
            for (int i = 0; i < 7; ++i) {
                float4 w = w0[i];
                float4 v = w1[i];
                float4 x0 = xa[i];
                float4 x1 = xb[i];
                FMA4(a00, w, x0); FMA4(a01, v, x0);
                FMA4(a10, w, x1); FMA4(a11, v, x1);
            }
            A0[A_CO + lane] = ftanh(red4(a00));
            A1[A_CO + lane] = ftanh(red4(a10));
            if (lane < 26) {
                A0[A_CO + 64 + lane] = ftanh(red4(a01));
                A1[A_CO + 64 + lane] = ftanh(red4(a11));
            }
        }
        __syncthreads();

        // ---- P7: out_c = tanh(CO @ oc_w^T + b) (k-split); carry update
        {
            const int half = lane >> 5, sub = lane & 31;
            const float4* xa = (const float4*)(A0 + A_CO + half * 48);
            const float4* xb = (const float4*)(A1 + A_CO + half * 48);
            const float4* w4 = (const float4*)(sm + OW_OC + sub * 100 + half * 48);
            float4 a0 = {0.f, 0.f, 0.f, 0.f};
            float4 a1 = {0.f, 0.f, 0.f, 0.f};
            #pragma unroll
            for (int i = 0; i < 12; ++i) {
                float4 w = w4[i];
                float4 x0 = xa[i]; FMA4(a0, w, x0);
                float4 x1 = xb[i]; FMA4(a1, w, x1);
            }
            float p0 = red4(a0); p0 += __shfl_xor(p0, 32);
            float p1 = red4(a1); p1 += __shfl_xor(p1, 32);
            if (lane < 27) {
                A0[A_OC + lane] = ftanh(p0 + b_oc);
                A1[A_OC + lane] = ftanh(p1 + b_oc);
            }
            if (lane < 30) {
                M0 = A0[A_CO + 30 + lane];  D0 = A0[A_CO + 60 + lane];
                M1 = A1[A_CO + 30 + lane];  D1 = A1[A_CO + 60 + lane];
                A0[A_COMB + 30 + lane] = M0;
                A1[A_COMB + 30 + lane] = M1;
            }
        }
        __syncthreads();

        // ---- P8: decision = tanh(OC @ oe_w^T + b)
        if (lane < 30) {
            const float4* xa = (const float4*)(A0 + A_OC);
            const float4* xb = (const float4*)(A1 + A_OC);
            const float4* w4 = (const float4*)(sm + OW_OE + lane * 28);
            float4 a0 = {b_oe, 0.f, 0.f, 0.f};
            float4 a1 = {b_oe, 0.f, 0.f, 0.f};
            #pragma unroll
            for (int i = 0; i < 7; ++i) {
                float4 w = w4[i];
                float4 x0 = xa[i]; FMA4(a0, w, x0);
                float4 x1 = xb[i]; FMA4(a1, w, x1);
            }
            A0[A_DEC + lane] = ftanh(red4(a0));
            A1[A_DEC + lane] = ftanh(red4(a1));
        }
        __syncthreads();

        // ---- P9: action -> global; write next obs
        if (lane < 4) {
            const float4* xa = (const float4*)(A0 + A_DEC);
            const float4* xb = (const float4*)(A1 + A_DEC);
            const float4* w4 = (const float4*)(sm + OW_OUT + lane * 36);
            float4 a0 = {b_out, 0.f, 0.f, 0.f};
            float4 a1 = {b_out, 0.f, 0.f, 0.f};
            #pragma unroll
            for (int i = 0; i < 8; ++i) {
                float4 w = w4[i];
                float4 x0 = xa[i]; FMA4(a0, w, x0);
                float4 x1 = xb[i]; FMA4(a1, w, x1);
            }
            out[((size_t)t * NB + row0) * 4 + lane] = red4(a0);
            out[((size_t)t * NB + row1) * 4 + lane] = red4(a1);
        }
        if (lane < 8 && t + 1 < TS) {
            A0[A_OBS + lane] = nxt0;
            A1[A_OBS + lane] = nxt1;
        }
        __syncthreads();
    }
}

extern "C" void kernel_launch(void* const* d_in, const int* in_sizes, int n_in,
                              void* d_out, int out_size, void* d_ws, size_t ws_size,
                              hipStream_t stream) {
    const float* obs        = (const float*)d_in[0];
    const float* sense_w    = (const float*)d_in[1];
    const float* sense_b    = (const float*)d_in[2];
    const float* compress_w = (const float*)d_in[3];
    const float* compress_b = (const float*)d_in[4];
    const float* expand_w   = (const float*)d_in[5];
    const float* expand_b   = (const float*)d_in[6];
    const float* gru_z_w    = (const float*)d_in[7];
    const float* gru_z_b    = (const float*)d_in[8];
    const float* gru_r_w    = (const float*)d_in[9];
    const float* gru_r_b    = (const float*)d_in[10];
    const float* gru_h_w    = (const float*)d_in[11];
    const float* gru_h_b    = (const float*)d_in[12];
    const float* ic_w       = (const float*)d_in[13];
    const float* ic_b       = (const float*)d_in[14];
    const float* iS_w       = (const float*)d_in[15];
    const float* iS_b       = (const float*)d_in[16];
    const float* iM_w       = (const float*)d_in[17];
    const float* iM_b       = (const float*)d_in[18];
    const float* iD_w       = (const float*)d_in[19];
    const float* iD_b       = (const float*)d_in[20];
    const float* phi_w      = (const float*)d_in[21];
    const float* phi_b      = (const float*)d_in[22];
    const float* oc_w       = (const float*)d_in[23];
    const float* oc_b       = (const float*)d_in[24];
    const float* oe_w       = (const float*)d_in[25];
    const float* oe_b       = (const float*)d_in[26];
    const float* out_w      = (const float*)d_in[27];
    const float* out_b      = (const float*)d_in[28];
    float* out = (float*)d_out;

    size_t shmem = (size_t)SM_TOTAL * sizeof(float);
    (void)hipFuncSetAttribute((const void*)anima_kernel,
                              hipFuncAttributeMaxDynamicSharedMemorySize, (int)shmem);
    anima_kernel<<<dim3(NB / NROWS_BLK), dim3(256), shmem, stream>>>(
        obs, sense_w, sense_b, compress_w, compress_b, expand_w, expand_b,
        gru_z_w, gru_z_b, gru_r_w, gru_r_b, gru_h_w, gru_h_b,
        ic_w, ic_b, iS_w, iS_b, iM_w, iM_b, iD_w, iD_b,
        phi_w, phi_b, oc_w, oc_b, oe_w, oe_b, out_w, out_b, out);
}